// Round 1
// baseline (136.488 us; speedup 1.0000x reference)
//
#include <hip/hip_runtime.h>
#include <math.h>

#define N_NODES 50000
#define N_EDGES 800000
#define IN_FEAT 128
#define HEADS   4
#define UNITS   16
#define OUTF    64          // HEADS*UNITS
#define LEAKY   0.2f

#define NB      196         // buckets: rcv>>8, 256 nodes each
#define BCAP    5120        // bucket capacity
#define GEMM_BLKS 782       // ceil(N_NODES/64)
#define A_BLOCKS  391       // ceil(N_EDGES/2048)
#define EPB     8           // edges per thread in phase A

typedef __attribute__((ext_vector_type(8))) short bf16x8;
typedef __attribute__((ext_vector_type(4))) float f32x4;

__device__ __forceinline__ unsigned short f2bf(float f) {
    unsigned u = __float_as_uint(f);
    unsigned r = u + 0x7FFFu + ((u >> 16) & 1u);   // RNE
    return (unsigned short)(r >> 16);
}

union SharedU {
    struct { unsigned short xl[64 * 136]; unsigned short wt[64 * 136]; } g; // 34816 B
    struct { int2 stage[2048]; int hist[256], s[256], excl[256],
             gbase[256], cur[256]; } a;                                     // 21504 B
};

// ---- fused: [h = x@W (MFMA bf16) + att scalars] | [bucket scatter] ----
// W transpose (fp32 -> bf16, [k][c] -> [c][k]) is done in-block: W is 32 KB,
// L2-resident after the first blocks touch it; saves the wt_prep launch + the
// Wt_g global round-trip.
__global__ __launch_bounds__(256) void fused_gemm_bucketA(const float* __restrict__ x,
                                                          const float* __restrict__ W,
                                                          const float* __restrict__ w1,
                                                          const float* __restrict__ w2,
                                                          const int2* __restrict__ ei,
                                                          unsigned short* __restrict__ hg,
                                                          float* __restrict__ a1,
                                                          float* __restrict__ a2,
                                                          int* __restrict__ bucket_cnt,
                                                          int2* __restrict__ buckets) {
    __shared__ SharedU sh;
    const int t = threadIdx.x;

    if (blockIdx.x >= GEMM_BLKS) {
        // ---------------- phase A: bucket scatter with LDS reorder ----------
        const int e0 = (blockIdx.x - GEMM_BLKS) * 2048;
        sh.a.hist[t] = 0;
        __syncthreads();

        int2 ed[EPB]; int bk[EPB];
        #pragma unroll
        for (int j = 0; j < EPB; ++j) {
            int e = e0 + t + j * 256;
            if (e < N_EDGES) {
                ed[j] = ei[e];
                bk[j] = ed[j].y >> 8;
                atomicAdd(&sh.a.hist[bk[j]], 1);
            } else bk[j] = -1;
        }
        __syncthreads();
        int v = sh.a.hist[t];
        sh.a.s[t] = v;
        __syncthreads();
        #pragma unroll
        for (int off = 1; off < 256; off <<= 1) {
            int u = (t >= off) ? sh.a.s[t - off] : 0;
            __syncthreads();
            sh.a.s[t] += u;
            __syncthreads();
        }
        sh.a.excl[t] = sh.a.s[t] - v;
        sh.a.cur[t] = 0;
        if (t < NB) sh.a.gbase[t] = atomicAdd(&bucket_cnt[t], v);
        __syncthreads();
        #pragma unroll
        for (int j = 0; j < EPB; ++j) {
            if (bk[j] >= 0) {
                int p = sh.a.excl[bk[j]] + atomicAdd(&sh.a.cur[bk[j]], 1);
                sh.a.stage[p] = ed[j];
            }
        }
        __syncthreads();
        const int total = min(2048, N_EDGES - e0);
        for (int i = t; i < total; i += 256) {
            int2 vv = sh.a.stage[i];
            int b = vv.y >> 8;
            buckets[(size_t)b * BCAP + sh.a.gbase[b] + (i - sh.a.excl[b])] = vv;
        }
        return;
    }

    // ---------------- MFMA gemm: 64 nodes x 64 cols, 4 waves ----------------
    const int node0 = blockIdx.x * 64;
    unsigned short* xl = sh.g.xl;   // [64][136] bf16 (pad 8)
    unsigned short* wt = sh.g.wt;   // [64][136] bf16

    #pragma unroll
    for (int it = 0; it < 8; ++it) {
        int idx = t + 256 * it;
        int r = idx >> 5, q = idx & 31;
        int node = node0 + r;
        float4 v = make_float4(0.f, 0.f, 0.f, 0.f);
        if (node < N_NODES) v = *(const float4*)(x + (size_t)node * IN_FEAT + q * 4);
        ushort4 b;
        b.x = f2bf(v.x); b.y = f2bf(v.y); b.z = f2bf(v.z); b.w = f2bf(v.w);
        *(ushort4*)&xl[r * 136 + q * 4] = b;
    }
    {
        // in-block W transpose: W[k][c] fp32 -> wt[c][k] bf16
        const float4* W4 = (const float4*)W;
        #pragma unroll
        for (int it = 0; it < 8; ++it) {
            int idx4 = t + 256 * it;          // 0..2047, covers 128x64 floats
            float4 v = W4[idx4];
            int flat = idx4 * 4;
            int k = flat >> 6, c = flat & 63; // 4 consecutive c, same k
            wt[(c + 0) * 136 + k] = f2bf(v.x);
            wt[(c + 1) * 136 + k] = f2bf(v.y);
            wt[(c + 2) * 136 + k] = f2bf(v.z);
            wt[(c + 3) * 136 + k] = f2bf(v.w);
        }
    }
    __syncthreads();

    const int lane = t & 63, wv = t >> 6;
    const int m = lane & 15, quad = lane >> 4;
    const int n0 = wv * 16;                       // wave's 16-node slab

    f32x4 acc[4] = {{0,0,0,0},{0,0,0,0},{0,0,0,0},{0,0,0,0}};
    #pragma unroll
    for (int kc = 0; kc < 4; ++kc) {
        bf16x8 af = *(bf16x8*)&xl[(n0 + m) * 136 + kc * 32 + quad * 8];
        #pragma unroll
        for (int ct = 0; ct < 4; ++ct) {
            bf16x8 bfr = *(bf16x8*)&wt[(ct * 16 + m) * 136 + kc * 32 + quad * 8];
            acc[ct] = __builtin_amdgcn_mfma_f32_16x16x32_bf16(af, bfr, acc[ct], 0, 0, 0);
        }
    }

    // a1/a2 from fp32 accumulators: head == ct; reduce over 16 cols (lane&15)
    #pragma unroll
    for (int ct = 0; ct < 4; ++ct) {
        const float u1 = w1[ct * 16 + m];
        const float u2 = w2[ct * 16 + m];
        #pragma unroll
        for (int r = 0; r < 4; ++r) {
            float p1 = acc[ct][r] * u1;
            float p2 = acc[ct][r] * u2;
            p1 += __shfl_xor(p1, 1, 64); p1 += __shfl_xor(p1, 2, 64);
            p1 += __shfl_xor(p1, 4, 64); p1 += __shfl_xor(p1, 8, 64);
            p2 += __shfl_xor(p2, 1, 64); p2 += __shfl_xor(p2, 2, 64);
            p2 += __shfl_xor(p2, 4, 64); p2 += __shfl_xor(p2, 8, 64);
            if (m == 0) {
                int node = node0 + n0 + quad * 4 + r;
                if (node < N_NODES) {
                    a1[node * 4 + ct] = p1;
                    a2[node * 4 + ct] = p2;
                }
            }
        }
    }

    // h epilogue: C-layout -> LDS bf16 [64][72] -> coalesced uint4 stores
    __syncthreads();
    unsigned short* hl = sh.g.xl;                 // reuse: 64*72 = 4608 ushort
    #pragma unroll
    for (int ct = 0; ct < 4; ++ct)
        #pragma unroll
        for (int r = 0; r < 4; ++r)
            hl[(n0 + quad * 4 + r) * 72 + ct * 16 + m] = f2bf(acc[ct][r]);
    __syncthreads();
    #pragma unroll
    for (int it = 0; it < 2; ++it) {
        int u = t + 256 * it;                     // 512 units: 64 rows x 8 groups
        int r = u >> 3, cg = u & 7;               // each group = 8 cols (uint4)
        int node = node0 + r;
        if (node < N_NODES)
            *(uint4*)&hg[(size_t)node * OUTF + cg * 8] = *(uint4*)&hl[r * 72 + cg * 8];
    }
}

// ---- phase B: per-bucket counting sort -> CSR + fused attention scalars ----
// 1024 threads (16 waves/CU vs previous 4) for latency hiding; bucket staged
// in LDS so `buckets` is read from global exactly once; e = exp(leaky(a1+a2))
// computed here (snd AND rcv both known) and stored per edge as float4 so the
// gather kernel loses its dependent random a1 gather + expf entirely.
__global__ __launch_bounds__(1024) void bucketB(const int2* __restrict__ buckets,
                                                const int* __restrict__ bucket_cnt,
                                                const float* __restrict__ a1,
                                                const float* __restrict__ a2,
                                                int* __restrict__ edge_snd,
                                                float* __restrict__ edge_e,
                                                int* __restrict__ rs,
                                                int* __restrict__ re) {
    __shared__ int hist[256], cur[256], s[256];
    __shared__ int2 stage[BCAP];                  // 40 KB
    const int b = blockIdx.x;
    const int t = threadIdx.x;
    const int cnt = bucket_cnt[b];
    if (t < 256) hist[t] = 0;
    __syncthreads();
    for (int i = t; i < cnt; i += 1024) {
        int2 vv = buckets[(size_t)b * BCAP + i];
        stage[i] = vv;
        atomicAdd(&hist[vv.y & 255], 1);
    }
    __syncthreads();
    if (t < 256) s[t] = hist[t];
    __syncthreads();
    #pragma unroll
    for (int off = 1; off < 256; off <<= 1) {
        int u = (t < 256 && t >= off) ? s[t - off] : 0;
        __syncthreads();
        if (t < 256) s[t] += u;
        __syncthreads();
    }
    if (t < 256) {
        const int v = hist[t];
        const int excl = s[t] - v;
        cur[t] = excl;
        const int node = b * 256 + t;
        if (node < N_NODES) {
            rs[node] = b * BCAP + excl;
            re[node] = b * BCAP + excl + v;
        }
    }
    __syncthreads();
    for (int i = t; i < cnt; i += 1024) {
        int2 vv = stage[i];
        int p = atomicAdd(&cur[vv.y & 255], 1);
        // attention scalars for all 4 heads (same fp32 math as before)
        float4 s1 = *(const float4*)(a1 + (size_t)vv.x * 4);   // random, L2 (800 KB)
        float4 s2 = *(const float4*)(a2 + (size_t)vv.y * 4);   // 4 KB window, L1-hot
        float t0 = s1.x + s2.x; t0 = t0 > 0.f ? t0 : LEAKY * t0;
        float t1 = s1.y + s2.y; t1 = t1 > 0.f ? t1 : LEAKY * t1;
        float t2 = s1.z + s2.z; t2 = t2 > 0.f ? t2 : LEAKY * t2;
        float t3 = s1.w + s2.w; t3 = t3 > 0.f ? t3 : LEAKY * t3;
        float4 e4 = make_float4(__expf(t0), __expf(t1), __expf(t2), __expf(t3));
        size_t q = (size_t)b * BCAP + p;
        edge_snd[q] = vv.x;
        *(float4*)(edge_e + q * 4) = e4;
    }
}

// ---- fused softmax+aggregation: wave/node, 8 edge slots x uint4 (8 cols) ----
// Per edge, only the 128 B h-row read is random now; edge_snd/edge_e are
// coalesced sequential streams (chain: stream load -> h gather -> fma).
__global__ __launch_bounds__(256, 8) void gather_kernel(const int* __restrict__ rs,
                                                        const int* __restrict__ re,
                                                        const int* __restrict__ edge_snd,
                                                        const float* __restrict__ edge_e,
                                                        const unsigned short* __restrict__ h,
                                                        float* __restrict__ out) {
    const int wave = threadIdx.x >> 6;
    const int lane = threadIdx.x & 63;
    const int n = blockIdx.x * 4 + wave;
    if (n >= N_NODES) return;
    const int sub  = lane >> 3;                    // edge slot 0..7
    const int li   = lane & 7;                     // 8-col group
    const int head = li >> 1;
    const int base = rs[n];
    const int end  = re[n];
    if (end <= base) {
        if (sub == 0) {
            *(float4*)(out + (size_t)n * OUTF + li * 8)     = make_float4(0.f, 0.f, 0.f, 0.f);
            *(float4*)(out + (size_t)n * OUTF + li * 8 + 4) = make_float4(0.f, 0.f, 0.f, 0.f);
        }
        return;
    }
    const uint4* h4 = (const uint4*)h;             // row = 8 uint4s

    float acc[8] = {0.f,0.f,0.f,0.f,0.f,0.f,0.f,0.f};
    float den = 0.f;

    for (int i = base; i < end; i += 16) {
        #pragma unroll
        for (int g = 0; g < 2; ++g) {
            int eraw = i + g * 8 + sub;
            int eidx = min(eraw, end - 1);
            int s = edge_snd[eidx];
            float ev = edge_e[(size_t)eidx * 4 + head];
            float e = (eraw < end) ? ev : 0.f;
            uint4 hv = h4[(unsigned)(s * 8 + li)];
            const unsigned hw[4] = {hv.x, hv.y, hv.z, hv.w};
            #pragma unroll
            for (int q = 0; q < 4; ++q) {
                acc[q*2+0] = fmaf(e, __uint_as_float(hw[q] << 16),         acc[q*2+0]);
                acc[q*2+1] = fmaf(e, __uint_as_float(hw[q] & 0xFFFF0000u), acc[q*2+1]);
            }
            den += e;
        }
    }

    // reduce across the 8 edge slots (lane bits 3,4,5)
    #pragma unroll
    for (int off = 8; off <= 32; off <<= 1) {
        #pragma unroll
        for (int q = 0; q < 8; ++q) acc[q] += __shfl_xor(acc[q], off, 64);
        den += __shfl_xor(den, off, 64);
    }

    if (sub == 0) {
        float inv = 1.f / den;
        *(float4*)(out + (size_t)n * OUTF + li * 8) =
            make_float4(acc[0] * inv, acc[1] * inv, acc[2] * inv, acc[3] * inv);
        *(float4*)(out + (size_t)n * OUTF + li * 8 + 4) =
            make_float4(acc[4] * inv, acc[5] * inv, acc[6] * inv, acc[7] * inv);
    }
}

extern "C" void kernel_launch(void* const* d_in, const int* in_sizes, int n_in,
                              void* d_out, int out_size, void* d_ws, size_t ws_size,
                              hipStream_t stream) {
    const float* x  = (const float*)d_in[0];
    const int2*  ei = (const int2*)d_in[1];
    const float* W  = (const float*)d_in[2];
    const float* w1 = (const float*)d_in[3];
    const float* w2 = (const float*)d_in[4];
    float* out = (float*)d_out;

    // workspace layout (bytes):
    // h bf16 6.4M | a1 0.8M | a2 0.8M | buckets 8.03M | edge_e 16.06M |
    // edge_snd 4.01M | rs 200K | re 200K | bucket_cnt 784B   (~36.3 MB total)
    unsigned short* h = (unsigned short*)d_ws;
    float* a1         = (float*)(h + (size_t)N_NODES * OUTF);
    float* a2         = a1 + (size_t)N_NODES * HEADS;
    int2*  buckets    = (int2*)(a2 + (size_t)N_NODES * HEADS);
    float* edge_e     = (float*)(buckets + (size_t)NB * BCAP);
    int*   edge_snd   = (int*)(edge_e + (size_t)NB * BCAP * 4);
    int*   rs         = edge_snd + (size_t)NB * BCAP;
    int*   re         = rs + N_NODES;
    int*   bucket_cnt = re + N_NODES;

    hipMemsetAsync(bucket_cnt, 0, NB * sizeof(int), stream);
    fused_gemm_bucketA<<<GEMM_BLKS + A_BLOCKS, 256, 0, stream>>>(x, W, w1, w2, ei,
                                                                 h, a1, a2,
                                                                 bucket_cnt, buckets);
    bucketB<<<NB, 1024, 0, stream>>>(buckets, bucket_cnt, a1, a2,
                                     edge_snd, edge_e, rs, re);
    gather_kernel<<<(N_NODES + 3) / 4, 256, 0, stream>>>(rs, re, edge_snd, edge_e, h, out);
}